// Round 10
// baseline (102.726 us; speedup 1.0000x reference)
//
#include <hip/hip_runtime.h>
#include <stdint.h>

using u16 = unsigned short;
using u32 = unsigned int;
using bf16x8 = __bf16 __attribute__((ext_vector_type(8)));
using f32x4  = float __attribute__((ext_vector_type(4)));

__device__ __forceinline__ float bflo(u32 u){ return __uint_as_float(u << 16); }
__device__ __forceinline__ float bfhi(u32 u){ return __uint_as_float(u & 0xffff0000u); }
__device__ __forceinline__ u16 f2bf(float f){
  u32 u = __float_as_uint(f);
  u += 0x7fffu + ((u >> 16) & 1u);
  return (u16)(u >> 16);
}
__device__ __forceinline__ u32 pk2(float a, float b){
  return (u32)f2bf(a) | ((u32)f2bf(b) << 16);
}
__device__ __forceinline__ void gload16(const void* g, void* l){
  __builtin_amdgcn_global_load_lds(
      (const __attribute__((address_space(1))) void*)(uintptr_t)(g),
      (__attribute__((address_space(3))) void*)(uintptr_t)(l), 16, 0, 0);
}

// ---------------- LN cast, 8 rows/block (2 rows/wave) + weight transpose ----------------
__global__ __launch_bounds__(256) void prepcast_k(
    const float* __restrict__ q, const float* __restrict__ k, const float* __restrict__ v,
    const float* __restrict__ lnw, const float* __restrict__ lnb,
    u16* __restrict__ xnq, u16* __restrict__ xnk, u16* __restrict__ xnv,
    const float* __restrict__ Win, const float* __restrict__ Wout,
    u16* __restrict__ WinT, u16* __restrict__ WoutT){
  __shared__ float tile[32][33];
  if (blockIdx.x >= 6144){
    int bi = blockIdx.x - 6144;            // 0..511
    int bz = bi >> 8; bi &= 255;
    int bx = bi & 15, by = bi >> 4;
    const float* src = bz ? Wout : Win;
    u16* dst = bz ? WoutT : WinT;
    int tx = threadIdx.x & 31, ty = threadIdx.x >> 5;
    int c0 = bx * 32, r0 = by * 32;
#pragma unroll
    for (int i = 0; i < 4; ++i)
      tile[ty + i*8][tx] = src[(size_t)(r0 + ty + i*8)*512 + c0 + tx];
    __syncthreads();
#pragma unroll
    for (int i = 0; i < 4; ++i)
      dst[(size_t)(c0 + ty + i*8)*512 + r0 + tx] = f2bf(tile[tx][ty + i*8]);
    return;
  }
  const int w = threadIdx.x >> 6, l = threadIdx.x & 63;
  int rb = blockIdx.x * 8;
  int r1 = rb + w, r2 = rb + 4 + w;        // same source array (8-row group)
  const float* x = (r1 < 16384) ? q : (r1 < 32768) ? k : v;
  u16* xo = (r1 < 16384) ? xnq : (r1 < 32768) ? xnk : xnv;
  int a1 = r1 & 16383, a2 = r2 & 16383;
  const float* p1 = x + (size_t)a1*512 + l*8;
  const float* p2 = x + (size_t)a2*512 + l*8;
  float4 a = *(const float4*)p1, c = *(const float4*)(p1 + 4);
  float4 d = *(const float4*)p2, e = *(const float4*)(p2 + 4);
  float s1 = ((a.x+a.y)+(a.z+a.w)) + ((c.x+c.y)+(c.z+c.w));
  float q1 = ((a.x*a.x+a.y*a.y)+(a.z*a.z+a.w*a.w)) + ((c.x*c.x+c.y*c.y)+(c.z*c.z+c.w*c.w));
  float s2 = ((d.x+d.y)+(d.z+d.w)) + ((e.x+e.y)+(e.z+e.w));
  float q2 = ((d.x*d.x+d.y*d.y)+(d.z*d.z+d.w*d.w)) + ((e.x*e.x+e.y*e.y)+(e.z*e.z+e.w*e.w));
#pragma unroll
  for (int off = 32; off; off >>= 1){
    s1 += __shfl_xor(s1, off); q1 += __shfl_xor(q1, off);
    s2 += __shfl_xor(s2, off); q2 += __shfl_xor(q2, off);
  }
  float mu1 = s1 * (1.f/512.f);
  float rs1 = rsqrtf(q1 * (1.f/512.f) - mu1*mu1 + 1e-5f);
  float mu2 = s2 * (1.f/512.f);
  float rs2 = rsqrtf(q2 * (1.f/512.f) - mu2*mu2 + 1e-5f);
  float4 w0 = *(const float4*)(lnw + l*8), w1 = *(const float4*)(lnw + l*8 + 4);
  float4 b0 = *(const float4*)(lnb + l*8), b1 = *(const float4*)(lnb + l*8 + 4);
  uint4 pk;
  pk.x = pk2((a.x-mu1)*rs1*w0.x + b0.x, (a.y-mu1)*rs1*w0.y + b0.y);
  pk.y = pk2((a.z-mu1)*rs1*w0.z + b0.z, (a.w-mu1)*rs1*w0.w + b0.w);
  pk.z = pk2((c.x-mu1)*rs1*w1.x + b1.x, (c.y-mu1)*rs1*w1.y + b1.y);
  pk.w = pk2((c.z-mu1)*rs1*w1.z + b1.z, (c.w-mu1)*rs1*w1.w + b1.w);
  *(uint4*)((char*)xo + (size_t)a1*1024 + l*16) = pk;
  pk.x = pk2((d.x-mu2)*rs2*w0.x + b0.x, (d.y-mu2)*rs2*w0.y + b0.y);
  pk.y = pk2((d.z-mu2)*rs2*w0.z + b0.z, (d.w-mu2)*rs2*w0.w + b0.w);
  pk.z = pk2((e.x-mu2)*rs2*w1.x + b1.x, (e.y-mu2)*rs2*w1.y + b1.y);
  pk.w = pk2((e.z-mu2)*rs2*w1.z + b1.z, (e.w-mu2)*rs2*w1.w + b1.w);
  *(uint4*)((char*)xo + (size_t)a2*1024 + l*16) = pk;
}

// ---------------- deep-pipelined bf16 GEMM: C[r][c] = sum_k A[r][k]*B[c][k] ----------------
// BK=32, 4 LDS buffers (64KB), 3-step prefetch, counted vmcnt across raw barriers (T3+T4).
// MAP 0: bx=bid&127, by=bid>>7.  MAP 1: j=bid>>3; bx=j&3; by=(bid&7)+8*(j>>2).
// FSTAT: 0 none, 1 per-row-per-head, 2 per-col-per-head.  F32OUT: fp32 + bias.
template<int MAP, int FSTAT, int F32OUT>
__device__ __forceinline__ void gemm_body(
    const u16* __restrict__ A, const u16* __restrict__ B,
    u16* __restrict__ C, float* __restrict__ Cf,
    float* __restrict__ stat, const float* __restrict__ bias,
    int ldC, int bid, char* sM){
  const int t = threadIdx.x, w = t >> 6, l = t & 63;
  const int wr = w >> 1, wc = w & 1;
  const int lr = l & 15, lg = l >> 4;
  int bx, by;
  if (MAP == 0){ bx = bid & 127; by = bid >> 7; }
  else { int j = bid >> 3; bx = j & 3; by = (bid & 7) + 8*(j >> 2); }
  const int row0 = bx*128, col0 = by*128;

  // staging: slot s -> (row = 2*(s>>3)+(e>>2), k16 = e&3), e = (s&7)^((s>>3)&7); slots {t, t+256}
  const int spr = t >> 3, se = (t & 7) ^ (spr & 7);
  const int srow = spr*2 + (se >> 2), sk16 = se & 3;
  const char* Ap0 = (const char*)A + ((size_t)(row0 + srow) << 10) + sk16*16;
  const char* Bp0 = (const char*)B + ((size_t)(col0 + srow) << 10) + sk16*16;
  const int ldst = w*1024 + l*16;

  // fragment read: byte = (wr|wc)*4096 + m*1024 + (lr>>1)*128 + qf*16
  const int qf = ((((lr & 1) << 2) | lg) ^ ((lr >> 1) & 7)) * 16;
  const int afb = wr*4096 + (lr >> 1)*128 + qf;
  const int bfb = wc*4096 + (lr >> 1)*128 + qf;

  f32x4 acc[4][4] = {};

  auto STAGE = [&](int kt, int buf){
    char* d = sM + buf*16384;
    gload16(Ap0 + kt*64,         d + ldst);
    gload16(Ap0 + 65536 + kt*64, d + 4096 + ldst);
    gload16(Bp0 + kt*64,         d + 8192 + ldst);
    gload16(Bp0 + 65536 + kt*64, d + 12288 + ldst);
  };

  STAGE(0, 0); STAGE(1, 1); STAGE(2, 2);
#pragma unroll
  for (int kt = 0; kt < 16; ++kt){
    if (kt < 14)       asm volatile("s_waitcnt vmcnt(8)" ::: "memory");
    else if (kt == 14) asm volatile("s_waitcnt vmcnt(4)" ::: "memory");
    else               asm volatile("s_waitcnt vmcnt(0)" ::: "memory");
    __builtin_amdgcn_s_barrier();
    __builtin_amdgcn_sched_barrier(0);
    if (kt < 13) STAGE(kt + 3, (kt + 3) & 3);
    const char* aR = sM + (kt & 3)*16384;
    const char* bR = aR + 8192;
    bf16x8 af[4], bfg[4];
#pragma unroll
    for (int m = 0; m < 4; ++m) af[m]  = *(const bf16x8*)(aR + afb + m*1024);
#pragma unroll
    for (int n = 0; n < 4; ++n) bfg[n] = *(const bf16x8*)(bR + bfb + n*1024);
#pragma unroll
    for (int m = 0; m < 4; ++m)
#pragma unroll
      for (int n = 0; n < 4; ++n)
        acc[m][n] = __builtin_amdgcn_mfma_f32_16x16x32_bf16(af[m], bfg[n], acc[m][n], 0, 0, 0);
  }

  // epilogue: D row-in-tile = lg*4+q, col-in-tile = lr
  float cs[4] = {}, cs2[4] = {};
#pragma unroll
  for (int m = 0; m < 4; ++m){
#pragma unroll
    for (int qq = 0; qq < 4; ++qq){
      int ri = wr*64 + m*16 + lg*4 + qq;
      float fv[4];
#pragma unroll
      for (int n = 0; n < 4; ++n){
        int ci = wc*64 + n*16 + lr;
        fv[n] = acc[m][n][qq];
        if (F32OUT) Cf[(size_t)(row0 + ri)*ldC + (col0 + ci)] = fv[n] + bias[col0 + ci];
        else        C [(size_t)(row0 + ri)*ldC + (col0 + ci)] = f2bf(fv[n]);
        if (FSTAT == 2){ cs[n] += fv[n]; cs2[n] += fv[n]*fv[n]; }
      }
      if (FSTAT == 1){
        float s  = (fv[0]+fv[1]) + (fv[2]+fv[3]);
        float s2 = (fv[0]*fv[0]+fv[1]*fv[1]) + (fv[2]*fv[2]+fv[3]*fv[3]);
#pragma unroll
        for (int off = 1; off < 16; off <<= 1){ s += __shfl_xor(s, off); s2 += __shfl_xor(s2, off); }
        if (lr == 0){
          int head = (col0 >> 6) + wc;
          *(float2*)(stat + ((size_t)(row0 + ri)*8 + head)*2) = make_float2(s, s2);
        }
      }
    }
  }
  if (FSTAT == 2){
    int head = (row0 >> 6) + wr;
#pragma unroll
    for (int n = 0; n < 4; ++n){
      float s = cs[n], s2 = cs2[n];
      s += __shfl_xor(s, 16); s2 += __shfl_xor(s2, 16);
      s += __shfl_xor(s, 32); s2 += __shfl_xor(s2, 32);
      if (lg == 0){
        int tok = col0 + wc*64 + n*16 + lr;
        *(float2*)(stat + ((size_t)tok*8 + head)*2) = make_float2(s, s2);
      }
    }
  }
}

// ---------------- merged Q/K/V projection: 1536 blocks ----------------
__global__ __launch_bounds__(256) void proj_k(
    const u16* __restrict__ xnq, const u16* __restrict__ xnk, const u16* __restrict__ xnv,
    const u16* __restrict__ Wt,
    u16* __restrict__ fq, u16* __restrict__ kT, u16* __restrict__ vT,
    float* __restrict__ qstat, float* __restrict__ kstat){
  __shared__ __align__(16) char sM[65536];
  int bid = blockIdx.x;
  if (bid < 512)
    gemm_body<0,1,0>(xnq, Wt, fq, nullptr, qstat, nullptr, 512, bid, sM);
  else if (bid < 1024)
    gemm_body<1,2,0>(Wt, xnk, kT, nullptr, kstat, nullptr, 16384, bid - 512, sM);
  else
    gemm_body<1,0,0>(Wt, xnv, vT, nullptr, nullptr, nullptr, 16384, bid - 1024, sM);
}

// ---------------- out GEMM: C = ao @ WoutT^T + bias (f32) ----------------
__global__ __launch_bounds__(256) void outgemm_k(
    const u16* __restrict__ A, const u16* __restrict__ B,
    float* __restrict__ Cf, const float* __restrict__ bias){
  __shared__ __align__(16) char sM[65536];
  gemm_body<0,0,1>(A, B, nullptr, Cf, nullptr, bias, 512, blockIdx.x, sM);
}

// ---------------- attention: per (h,b), factored rank-64 form, MFMA ----------------
__global__ __launch_bounds__(512) void attn_k(
    const u16* __restrict__ fq, const u16* __restrict__ kT, const u16* __restrict__ vT,
    const float* __restrict__ qstat, const float* __restrict__ kstat,
    u16* __restrict__ ao,
    const float* __restrict__ cwr, const float* __restrict__ vwr){
  __shared__ __align__(16) char smem[131072 + 1664*4];
  float* sStat = (float*)(smem + 131072);
  float* sS1 = sStat + 1536;
  float* sS2 = sStat + 1600;

  const int t = threadIdx.x, w = t >> 6, l = t & 63;
  const int lr = l & 15, lg = l >> 4;
  const int h = blockIdx.x & 7, b = blockIdx.x >> 3;

  float cwv = 1.f/(1.f + __expf(-*cwr));
  float vwv = 1.f/(1.f + __expf(-*vwr));
  float cosw = 1.f - cwv - vwv;

  const char* kTb = (const char*)kT + (size_t)h*64*32768 + (size_t)b*1024;
  const char* vTb = (const char*)vT + (size_t)h*64*32768 + (size_t)b*1024;
#pragma unroll
  for (int ii = 0; ii < 8; ++ii){
    int c = ii*512 + t, d = c >> 6, u = c & 63;
    int so = d*32768 + ((u ^ (d & 7)) << 4);
    gload16(kTb + so, smem + ii*8192 + w*1024);
    gload16(vTb + so, smem + 65536 + ii*8192 + w*1024);
  }
  {
    float2 ksr = *(const float2*)(kstat + ((size_t)(b*512 + t)*8 + h)*2);
    float mk = ksr.x * (1.f/64.f);
    sStat[t]        = rsqrtf(ksr.y);
    sStat[512 + t]  = mk;
    sStat[1024 + t] = (ksr.y - 64.f*mk*mk) * (1.f/63.f);
  }
  __syncthreads();

  const int jt = (w >> 1), itp = (w & 1);
  f32x4 m2acc[2] = {}, m1acc[2] = {};
  {
    const int j = jt*16 + lr;
#pragma unroll
    for (int ks = 0; ks < 16; ++ks){
      int u = ks*4 + lg;
      bf16x8 af = *(const bf16x8*)(smem + 65536 + j*1024 + ((u ^ (j & 7)) << 4));
#pragma unroll
      for (int tt = 0; tt < 2; ++tt){
        int i = (itp*2 + tt)*16 + lr;
        bf16x8 bf = *(const bf16x8*)(smem + i*1024 + ((u ^ (i & 7)) << 4));
        m2acc[tt] = __builtin_amdgcn_mfma_f32_16x16x32_bf16(af, bf, m2acc[tt], 0, 0, 0);
      }
    }
  }
  {
    int j = t >> 3, g = t & 7;
    float p1 = 0.f, p2 = 0.f;
#pragma unroll
    for (int uu = 0; uu < 8; ++uu){
      int ut = g*8 + uu;
      uint4 uv = *(const uint4*)(smem + 65536 + j*1024 + ((ut ^ (j & 7)) << 4));
      int m0 = ut*8;
      float4 mk0 = *(const float4*)(sStat + 512 + m0);
      float4 mk1 = *(const float4*)(sStat + 512 + m0 + 4);
      float4 kv0 = *(const float4*)(sStat + 1024 + m0);
      float4 kv1 = *(const float4*)(sStat + 1024 + m0 + 4);
      float v0=bflo(uv.x),v1=bfhi(uv.x),v2=bflo(uv.y),v3=bfhi(uv.y);
      float v4=bflo(uv.z),v5=bfhi(uv.z),v6=bflo(uv.w),v7=bfhi(uv.w);
      p1 += v0*mk0.x + v1*mk0.y + v2*mk0.z + v3*mk0.w
          + v4*mk1.x + v5*mk1.y + v6*mk1.z + v7*mk1.w;
      p2 += v0*kv0.x + v1*kv0.y + v2*kv0.z + v3*kv0.w
          + v4*kv1.x + v5*kv1.y + v6*kv1.z + v7*kv1.w;
    }
#pragma unroll
    for (int off = 1; off < 8; off <<= 1){ p1 += __shfl_xor(p1, off); p2 += __shfl_xor(p2, off); }
    if (g == 0){ sS1[j] = p1; sS2[j] = p2; }
  }
  __syncthreads();

#pragma unroll
  for (int ii = 0; ii < 32; ++ii){
    int wd = ii*512 + t;
    int d = wd >> 8, o = wd & 255, ud = o >> 2, p = o & 3;
    int m0 = ((ud ^ (d & 7)) << 3) + p*2;
    u32 uv = *(u32*)(smem + wd*4);
    *(u32*)(smem + wd*4) = pk2(bflo(uv)*sStat[m0], bfhi(uv)*sStat[m0+1]);
  }
  __syncthreads();

  {
    const int j = jt*16 + lr;
#pragma unroll
    for (int ks = 0; ks < 16; ++ks){
      int u = ks*4 + lg;
      bf16x8 af = *(const bf16x8*)(smem + 65536 + j*1024 + ((u ^ (j & 7)) << 4));
#pragma unroll
      for (int tt = 0; tt < 2; ++tt){
        int i = (itp*2 + tt)*16 + lr;
        bf16x8 bf = *(const bf16x8*)(smem + i*1024 + ((u ^ (i & 7)) << 4));
        m1acc[tt] = __builtin_amdgcn_mfma_f32_16x16x32_bf16(af, bf, m1acc[tt], 0, 0, 0);
      }
    }
  }
  __syncthreads();

#pragma unroll
  for (int tt = 0; tt < 2; ++tt){
#pragma unroll
    for (int q = 0; q < 4; ++q){
      int j = jt*16 + lg*4 + q;
      int i = (itp*2 + tt)*16 + lr;
      int bo = j*128 + (((i >> 3) ^ (j & 7)) << 4) + (i & 7)*2;
      *(u16*)(smem + bo)        = f2bf(m1acc[tt][q]);
      *(u16*)(smem + 8192 + bo) = f2bf(m2acc[tt][q]);
    }
  }
  const char* fqb = (const char*)fq + (size_t)b*524288 + h*128;
#pragma unroll
  for (int ii = 0; ii < 8; ++ii){
    int c = ii*512 + t, n = c >> 3, u = c & 7;
    gload16(fqb + n*1024 + ((u ^ (n & 7)) << 4), smem + 65536 + ii*8192 + w*1024);
  }
  __syncthreads();

  float s1v[4], s2v[4];
#pragma unroll
  for (int nt = 0; nt < 4; ++nt){ s1v[nt] = sS1[nt*16 + lr]; s2v[nt] = sS2[nt*16 + lr]; }
  const float Bc = cwv * (1.f/64.f);

#pragma unroll
  for (int mt = 0; mt < 4; ++mt){
    f32x4 a1[4] = {}, a2[4] = {};
    const int n = w*64 + mt*16 + lr;
#pragma unroll
    for (int kk = 0; kk < 2; ++kk){
      int u = kk*4 + lg;
      bf16x8 af = *(const bf16x8*)(smem + 65536 + n*128 + ((u ^ (n & 7)) << 4));
#pragma unroll
      for (int nt = 0; nt < 4; ++nt){
        int j = nt*16 + lr;
        bf16x8 b1 = *(const bf16x8*)(smem + j*128 + ((u ^ (j & 7)) << 4));
        bf16x8 b2 = *(const bf16x8*)(smem + 8192 + j*128 + ((u ^ (j & 7)) << 4));
        a1[nt] = __builtin_amdgcn_mfma_f32_16x16x32_bf16(af, b1, a1[nt], 0, 0, 0);
        a2[nt] = __builtin_amdgcn_mfma_f32_16x16x32_bf16(af, b2, a2[nt], 0, 0, 0);
      }
    }
#pragma unroll
    for (int q = 0; q < 4; ++q){
      int nr = w*64 + mt*16 + lg*4 + q;
      float2 qs = *(const float2*)(qstat + ((size_t)(b*512 + nr)*8 + h)*2);
      float mq = qs.x * (1.f/64.f);
      float An = cosw * rsqrtf(qs.y);
      float Cn = -cwv * mq;
      float En = vwv * (1.f/64.f) * ((qs.y - 64.f*mq*mq) * (1.f/63.f));
      char* op = (char*)ao + ((size_t)(b*512 + nr)*512 + h*64)*2;
#pragma unroll
      for (int nt = 0; nt < 4; ++nt){
        float ov = An*a1[nt][q] + Bc*a2[nt][q] + Cn*s1v[nt] + En*s2v[nt];
        *(u16*)(op + (nt*16 + lr)*2) = f2bf(ov);
      }
    }
  }
}

// ---------------- launch ----------------
extern "C" void kernel_launch(void* const* d_in, const int* in_sizes, int n_in,
                              void* d_out, int out_size, void* d_ws, size_t ws_size,
                              hipStream_t stream){
  const float* q    = (const float*)d_in[0];
  const float* k    = (const float*)d_in[1];
  const float* v    = (const float*)d_in[2];
  const float* lnw  = (const float*)d_in[3];
  const float* lnb  = (const float*)d_in[4];
  const float* Win  = (const float*)d_in[5];
  const float* Wout = (const float*)d_in[6];
  const float* bout = (const float*)d_in[7];
  const float* cwr  = (const float*)d_in[8];
  const float* vwr  = (const float*)d_in[9];

  char* ws = (char*)d_ws;
  const size_t FB = (size_t)16384 * 512 * 2;   // 16 MiB bf16 buffer
  u16* xnq = (u16*)(ws);
  u16* xnk = (u16*)(ws + FB);
  u16* xnv = (u16*)(ws + 2*FB);
  u16* fq  = (u16*)(ws + 3*FB);
  u16* kT  = (u16*)(ws + 4*FB);
  u16* vT  = (u16*)(ws + 5*FB);
  u16* ao  = (u16*)(ws + 6*FB);
  u16* WinT  = (u16*)(ws + 7*FB);
  u16* WoutT = (u16*)(ws + 7*FB + 524288);
  float* qstat = (float*)d_out;            // scratch in d_out (dead before out-GEMM)
  float* kstat = qstat + 262144;

  // LN+cast q/k/v -> bf16 xn (8 rows/block), plus weight transposes
  prepcast_k<<<6656, 256, 0, stream>>>(q, k, v, lnw, lnb, xnq, xnk, xnv,
                                       Win, Wout, WinT, WoutT);

  // merged deep-pipelined projections
  proj_k<<<1536, 256, 0, stream>>>(xnq, xnk, xnv, WinT, fq, kT, vT, qstat, kstat);

  attn_k<<<256, 512, 0, stream>>>(fq, kT, vT, qstat, kstat, ao, cwr, vwr);

  outgemm_k<<<512, 256, 0, stream>>>(ao, WoutT, (float*)d_out, bout);
}